// Round 1
// baseline (88.396 us; speedup 1.0000x reference)
//
#include <hip/hip_runtime.h>

// Problem constants (from reference): NY,NX,NZ,C = 496,432,1,64; N=320000; B=4
#define NY_ 496
#define NX_ 432
#define NZ_ 1
#define C_ 64
#define NVOX_ 320000
#define BATCH_ 4
#define SPATIAL_ (NY_ * NX_ * NZ_)        // 214272 cells per batch
#define NCELLS_ (BATCH_ * SPATIAL_)       // 857088 total cells

// K1: init winner table (in d_ws) to -1
__global__ void gs_init_winner(int* __restrict__ winner) {
    int j = blockIdx.x * blockDim.x + threadIdx.x;
    if (j < NCELLS_) winner[j] = -1;
}

// K2: vote — last write wins == max voxel index wins (numpy fancy-assign semantics)
__global__ void gs_vote(const int* __restrict__ coors, int* __restrict__ winner) {
    int i = blockIdx.x * blockDim.x + threadIdx.x;
    if (i >= NVOX_) return;
    int4 czyx = *reinterpret_cast<const int4*>(coors + 4 * i); // [b, z, y, x]
    int b = czyx.x, z = czyx.y, y = czyx.z, x = czyx.w;
    int cell = ((b * NY_ + y) * NX_ + x) * NZ_ + z;
    atomicMax(&winner[cell], i);
}

// K3: output-centric fill. One thread per (b,y,x) cell, loops over 64 channels.
// Wave of 64 lanes covers 64 consecutive x -> every store is a coalesced 256B
// wave-write. vf row gathered per-lane as float4 (16B chunks, L1-resident).
// Branch-free: empty cells read row 0 (cached) and multiply by 0.
__global__ void gs_fill(const float* __restrict__ vf,
                        const int* __restrict__ winner,
                        float* __restrict__ out) {
    int cell = blockIdx.x * blockDim.x + threadIdx.x; // cell = b*SPATIAL + y*NX + x  (z=0)
    int b  = cell / SPATIAL_;
    int sp = cell - b * SPATIAL_;

    int w = winner[cell];
    float m = (w >= 0) ? 1.0f : 0.0f;
    int wi  = (w >= 0) ? w : 0;

    const float4* vrow = reinterpret_cast<const float4*>(vf + (size_t)wi * C_);
    float* outp = out + (size_t)b * C_ * SPATIAL_ + sp;

#pragma unroll
    for (int c4 = 0; c4 < C_ / 4; ++c4) {
        float4 v = vrow[c4];
        int c = c4 * 4;
        outp[(size_t)(c + 0) * SPATIAL_] = v.x * m;
        outp[(size_t)(c + 1) * SPATIAL_] = v.y * m;
        outp[(size_t)(c + 2) * SPATIAL_] = v.z * m;
        outp[(size_t)(c + 3) * SPATIAL_] = v.w * m;
    }
}

extern "C" void kernel_launch(void* const* d_in, const int* in_sizes, int n_in,
                              void* d_out, int out_size, void* d_ws, size_t ws_size,
                              hipStream_t stream) {
    const float* vf    = (const float*)d_in[0];  // (N, C) float32
    const int*   coors = (const int*)d_in[1];    // (N, 4) int32 [b,z,y,x]
    // d_in[2] = batch_size scalar (fixed at 4, baked into constants)
    float* out  = (float*)d_out;                 // (B, C, NY, NX, NZ) float32
    int* winner = (int*)d_ws;                    // NCELLS_ ints = 3.43 MB scratch

    gs_init_winner<<<(NCELLS_ + 255) / 256, 256, 0, stream>>>(winner);
    gs_vote<<<(NVOX_ + 255) / 256, 256, 0, stream>>>(coors, winner);
    gs_fill<<<NCELLS_ / 256, 256, 0, stream>>>(vf, winner, out); // 857088 % 256 == 0
}

// Round 3
// 74.290 us; speedup vs baseline: 1.1899x; 1.1899x over previous
//
#include <hip/hip_runtime.h>

// Problem constants (from reference): NY,NX,NZ,C = 496,432,1,64; N=320000; B=4
#define NY_ 496
#define NX_ 432
#define NZ_ 1
#define C_ 64
#define NVOX_ 320000
#define BATCH_ 4
#define SPATIAL_ (NY_ * NX_ * NZ_)        // 214272 cells per batch (mult of 4)
#define NCELLS_ (BATCH_ * SPATIAL_)       // 857088 total cells (mult of 1024)

typedef float f32x4 __attribute__((ext_vector_type(4)));
typedef int   i32x4 __attribute__((ext_vector_type(4)));

// K1: init winner table (in d_ws) to -1, vectorized 16B
__global__ void gs_init_winner(i32x4* __restrict__ winner4) {
    int j = blockIdx.x * blockDim.x + threadIdx.x;   // NCELLS_/4 = 214272 threads
    i32x4 v = {-1, -1, -1, -1};
    winner4[j] = v;
}

// K2: vote — last write wins == max voxel index wins (numpy fancy-assign semantics)
__global__ void gs_vote(const int* __restrict__ coors, int* __restrict__ winner) {
    int i = blockIdx.x * blockDim.x + threadIdx.x;
    if (i >= NVOX_) return;
    i32x4 czyx = *reinterpret_cast<const i32x4*>(coors + 4 * i); // [b, z, y, x]
    int b = czyx.x, z = czyx.y, y = czyx.z, x = czyx.w;
    int cell = ((b * NY_ + y) * NX_ + x) * NZ_ + z;
    atomicMax(&winner[cell], i);
}

// K3: output-centric fill. One thread per 4 consecutive cells (same batch, since
// SPATIAL_ % 4 == 0), all 64 channels. Per channel-quad: gather f32x4 from each
// of the 4 winner rows, 4x4 transpose in registers, 4x f32x4 nontemporal stores
// (16 B/lane -> 1 KB/wave-instruction, contiguous within each channel plane).
__global__ void gs_fill(const float* __restrict__ vf,
                        const int* __restrict__ winner,
                        float* __restrict__ out) {
    int t = blockIdx.x * blockDim.x + threadIdx.x;   // NCELLS_/4 threads
    int cell0 = t * 4;
    int b  = cell0 / SPATIAL_;
    int sp = cell0 - b * SPATIAL_;

    i32x4 w = *reinterpret_cast<const i32x4*>(winner + cell0);
    float m0 = (w.x >= 0) ? 1.0f : 0.0f;  int i0 = (w.x >= 0) ? w.x : 0;
    float m1 = (w.y >= 0) ? 1.0f : 0.0f;  int i1 = (w.y >= 0) ? w.y : 0;
    float m2 = (w.z >= 0) ? 1.0f : 0.0f;  int i2 = (w.z >= 0) ? w.z : 0;
    float m3 = (w.w >= 0) ? 1.0f : 0.0f;  int i3 = (w.w >= 0) ? w.w : 0;

    const f32x4* r0 = reinterpret_cast<const f32x4*>(vf + (size_t)i0 * C_);
    const f32x4* r1 = reinterpret_cast<const f32x4*>(vf + (size_t)i1 * C_);
    const f32x4* r2 = reinterpret_cast<const f32x4*>(vf + (size_t)i2 * C_);
    const f32x4* r3 = reinterpret_cast<const f32x4*>(vf + (size_t)i3 * C_);

    float* outp = out + (size_t)b * C_ * SPATIAL_ + sp;

#pragma unroll
    for (int c4 = 0; c4 < C_ / 4; ++c4) {
        f32x4 a = r0[c4];
        f32x4 bb = r1[c4];
        f32x4 c = r2[c4];
        f32x4 d = r3[c4];
        f32x4 o0 = {a.x * m0, bb.x * m1, c.x * m2, d.x * m3};
        f32x4 o1 = {a.y * m0, bb.y * m1, c.y * m2, d.y * m3};
        f32x4 o2 = {a.z * m0, bb.z * m1, c.z * m2, d.z * m3};
        f32x4 o3 = {a.w * m0, bb.w * m1, c.w * m2, d.w * m3};
        __builtin_nontemporal_store(o0, reinterpret_cast<f32x4*>(outp + (size_t)(4 * c4) * SPATIAL_));
        __builtin_nontemporal_store(o1, reinterpret_cast<f32x4*>(outp + (size_t)(4 * c4 + 1) * SPATIAL_));
        __builtin_nontemporal_store(o2, reinterpret_cast<f32x4*>(outp + (size_t)(4 * c4 + 2) * SPATIAL_));
        __builtin_nontemporal_store(o3, reinterpret_cast<f32x4*>(outp + (size_t)(4 * c4 + 3) * SPATIAL_));
    }
}

extern "C" void kernel_launch(void* const* d_in, const int* in_sizes, int n_in,
                              void* d_out, int out_size, void* d_ws, size_t ws_size,
                              hipStream_t stream) {
    const float* vf    = (const float*)d_in[0];  // (N, C) float32
    const int*   coors = (const int*)d_in[1];    // (N, 4) int32 [b,z,y,x]
    // d_in[2] = batch_size scalar (fixed at 4, baked into constants)
    float* out  = (float*)d_out;                 // (B, C, NY, NX, NZ) float32
    int* winner = (int*)d_ws;                    // NCELLS_ ints = 3.43 MB scratch

    gs_init_winner<<<NCELLS_ / 4 / 256, 256, 0, stream>>>((i32x4*)winner); // 837 blocks
    gs_vote<<<(NVOX_ + 255) / 256, 256, 0, stream>>>(coors, winner);
    gs_fill<<<NCELLS_ / 4 / 256, 256, 0, stream>>>(vf, winner, out);       // 837 blocks
}